// Round 7
// baseline (263.183 us; speedup 1.0000x reference)
//
#include <hip/hip_runtime.h>

#define D 256
#define K 1024
#define NVEC 65536
#define ROWS 32       // rows per block
#define GROUPC 256    // codes per group (per-wave slice = 64)
#define NG (K / GROUPC)
#define NKB (D / 32)  // 8 k-steps of 32
#define MARGIN 0.5f   // ~7 sigma of bf16 coarse-distance error
#define MAXP 384      // pair-list capacity (12/row avg)

typedef __attribute__((ext_vector_type(8))) __bf16 bf16x8;
typedef __attribute__((ext_vector_type(4))) float floatx4;

__device__ inline unsigned short f2bf(float f) {  // RNE fp32->bf16
    unsigned int u = __float_as_uint(f);
    unsigned int r = u + 0x7fffu + ((u >> 16) & 1u);
    return (unsigned short)(r >> 16);
}
__device__ inline float bf2f(unsigned short h) {
    return __uint_as_float((unsigned int)h << 16);
}
__device__ inline unsigned int fkey(float f) {    // order-preserving float->uint
    unsigned int b = __float_as_uint(f);
    return (b & 0x80000000u) ? ~b : (b | 0x80000000u);
}
__device__ inline float unfkey(unsigned int k) {
    unsigned int b = (k & 0x80000000u) ? (k & 0x7fffffffu) : ~k;
    return __uint_as_float(b);
}

// ws: cnorm fp32 [0,4KB) | lossAcc @4KB | cbf bf16 (B-fragment order) @8KB (512KB)
// cbf layout: code c -> g=c>>8, w=(c>>6)&3, j=(c>>4)&3, col=c&15 ; k -> kb=k>>5,
// quad=(k>>3)&3, h=k&7.  16B seg = S*64 + quad*16+col, S=((g*8+kb)*4+w)*4+j.
__global__ void vq_prep(const float* __restrict__ cb, float* __restrict__ cnorm,
                        unsigned short* __restrict__ cbf, float* __restrict__ lossAcc) {
    const int c = blockIdx.x;
    const int l = threadIdx.x;
    float4 v = *(const float4*)&cb[c * D + l * 4];
    float s = v.x * v.x + v.y * v.y + v.z * v.z + v.w * v.w;
#pragma unroll
    for (int off = 32; off > 0; off >>= 1) s += __shfl_down(s, off, 64);
    if (l == 0) cnorm[c] = s;
    const int g = c >> 8, w = (c >> 6) & 3, j = (c >> 4) & 3, col = c & 15;
    const int kb = l >> 3, quad = (l >> 1) & 3, h = (l & 1) * 4;
    const int S = ((g * 8 + kb) * 4 + w) * 4 + j;
    *(ushort4*)(cbf + (size_t)S * 512 + (quad * 16 + col) * 8 + h) =
        make_ushort4(f2bf(v.x), f2bf(v.y), f2bf(v.z), f2bf(v.w));
    if (c == 0 && l == 0) *lossAcc = 0.f;
}

__global__ __launch_bounds__(256, 6) void vq_fused(
        const float* __restrict__ x, const float* __restrict__ cb,
        const unsigned short* __restrict__ cbf, const float* __restrict__ cnorm,
        float* __restrict__ lossAcc, float* __restrict__ out)
{
    __shared__ __align__(16) unsigned short xs[ROWS * D];   // 16 KB, swizzled 16B segs
    __shared__ unsigned int rowMinU[ROWS];
    __shared__ unsigned long long rowBest[ROWS];
    __shared__ int pairs[MAXP];
    __shared__ int pcnt;
    __shared__ int widx[ROWS];
    __shared__ float wsum[4];

    const int tid = threadIdx.x;
    const int wave = tid >> 6;
    const int lane = tid & 63;
    const int quad = lane >> 4;
    const int col  = lane & 15;
    const int rowBase = blockIdx.x * ROWS;
    const float* xblk = x + (size_t)rowBase * D;

    if (tid < ROWS) { rowMinU[tid] = 0xFFFFFFFFu; rowBest[tid] = ~0ull; }
    if (tid == 0) pcnt = 0;

    // ---- stage x -> bf16 LDS once (seg slot = seg ^ row) ----
#pragma unroll
    for (int it = 0; it < 8; ++it) {
        int e = tid + it * 256;                 // 2048 float4
        int r = e >> 6;
        int d4 = (e & 63) << 2;
        float4 v = *(const float4*)&xblk[r * D + d4];
        int slot = (d4 >> 3) ^ r;
        *(ushort4*)&xs[r * D + slot * 8 + (d4 & 4)] =
            make_ushort4(f2bf(v.x), f2bf(v.y), f2bf(v.z), f2bf(v.w));
    }
    __syncthreads();

    // ---- coarse bf16 MFMA search: barrier-free K-loop, B direct from L2 ----
    for (int g = 0; g < NG; ++g) {
        floatx4 acc[2][4];
#pragma unroll
        for (int i = 0; i < 2; ++i)
#pragma unroll
            for (int j = 0; j < 4; ++j) acc[i][j] = (floatx4){0.f, 0.f, 0.f, 0.f};

#pragma unroll
        for (int kb = 0; kb < NKB; ++kb) {
            bf16x8 af[2], bfr[4];
#pragma unroll
            for (int i = 0; i < 2; ++i) {
                int r = i * 16 + col;
                int slot = (kb * 4 + quad) ^ r;
                af[i] = *(const bf16x8*)&xs[r * D + slot * 8];
            }
#pragma unroll
            for (int j = 0; j < 4; ++j) {
                int S = ((g * 8 + kb) * 4 + wave) * 4 + j;
                bfr[j] = *(const bf16x8*)(cbf + (size_t)S * 512 + lane * 8);
            }
#pragma unroll
            for (int j = 0; j < 4; ++j)
#pragma unroll
                for (int i = 0; i < 2; ++i)
                    acc[i][j] = __builtin_amdgcn_mfma_f32_16x16x32_bf16(af[i], bfr[j], acc[i][j], 0, 0, 0);
        }

        // ---- group epilogue: running per-row min, then candidate collect ----
        const int cbase = g * GROUPC + wave * 64;
        float cn[4];
#pragma unroll
        for (int j = 0; j < 4; ++j) cn[j] = cnorm[cbase + j * 16 + col];

#pragma unroll
        for (int i = 0; i < 2; ++i)
#pragma unroll
            for (int reg = 0; reg < 4; ++reg) {
                float v = cn[0] - 2.f * acc[i][0][reg];
#pragma unroll
                for (int j = 1; j < 4; ++j)
                    v = fminf(v, cn[j] - 2.f * acc[i][j][reg]);
#pragma unroll
                for (int off = 1; off < 16; off <<= 1)
                    v = fminf(v, __shfl_xor(v, off, 64));
                if (col == 0)
                    atomicMin(&rowMinU[i * 16 + quad * 4 + reg], fkey(v));
            }
        __syncthreads();   // tighten bound (stale/lower bound is superset-safe anyway)
#pragma unroll
        for (int i = 0; i < 2; ++i)
#pragma unroll
            for (int reg = 0; reg < 4; ++reg) {
                int row = i * 16 + quad * 4 + reg;
                float lim = unfkey(rowMinU[row]) + MARGIN;
#pragma unroll
                for (int j = 0; j < 4; ++j) {
                    float d2 = cn[j] - 2.f * acc[i][j][reg];
                    if (d2 < lim) {
                        int p = atomicAdd(&pcnt, 1);
                        if (p < MAXP) pairs[p] = (row << 10) | (cbase + j * 16 + col);
                    }
                }
            }
    }
    __syncthreads();
    const int np = pcnt;

    if (np <= MAXP) {
        // ---- exact fp32 rescore: 16 lane-teams of 16, one pair per team-step ----
        const int team = wave * 4 + quad;
        for (int p = team; p < np; p += 16) {
            int pr = pairs[p];
            int row = pr >> 10, code = pr & 1023;
            const float* xr = xblk + row * D + col * 16;
            const float* er = cb + (size_t)code * D + col * 16;
            float s = 0.f;
#pragma unroll
            for (int q = 0; q < 4; ++q) {
                float4 a = *(const float4*)(xr + q * 4);
                float4 b = *(const float4*)(er + q * 4);
                s += a.x * b.x + a.y * b.y + a.z * b.z + a.w * b.w;
            }
#pragma unroll
            for (int off = 1; off < 16; off <<= 1) s += __shfl_xor(s, off, 64);
            if (col == 0) {
                float dist = cnorm[code] - 2.f * s;
                atomicMin(&rowBest[row],
                          ((unsigned long long)fkey(dist) << 32) | (unsigned int)code);
            }
        }
    } else {
        // ---- overflow fallback (~never): exact full scan, 8 rows per wave ----
        for (int rr = 0; rr < 8; ++rr) {
            const int rl = wave * 8 + rr;
            float best = 3.4e38f;
            int bi = 0x7fffffff;
            for (int c = lane; c < K; c += 64) {
                float p = 0.f;
                for (int k = 0; k < D; ++k) p += xblk[rl * D + k] * cb[(size_t)c * D + k];
                float dist = cnorm[c] - 2.f * p;
                if (dist < best || (dist == best && c < bi)) { best = dist; bi = c; }
            }
#pragma unroll
            for (int off = 1; off < 64; off <<= 1) {
                float ob = __shfl_xor(best, off, 64);
                int oi = __shfl_xor(bi, off, 64);
                if (ob < best || (ob == best && oi < bi)) { best = ob; bi = oi; }
            }
            if (lane == 0)
                atomicMin(&rowBest[rl], ((unsigned long long)fkey(best) << 32) | (unsigned int)bi);
        }
    }
    __syncthreads();
    if (tid < ROWS) widx[tid] = (int)(rowBest[tid] & 0xffffffffu);
    __syncthreads();

    // ---- gather + loss (x read back from LDS bf16 — no HBM re-read) ----
    float part = 0.f;
#pragma unroll
    for (int it = 0; it < 8; ++it) {
        int e4 = tid + it * 256;              // ROWS*D/4 = 2048 float4
        int r = e4 >> 6, d4 = (e4 & 63) * 4;
        float4 q = *(const float4*)&cb[(size_t)widx[r] * D + d4];
        int slot = (d4 >> 3) ^ r;
        ushort4 xh = *(const ushort4*)&xs[r * D + slot * 8 + (d4 & 4)];
        *(float4*)&out[(size_t)rowBase * D + r * D + d4] = q;
        float a = q.x - bf2f(xh.x), b = q.y - bf2f(xh.y);
        float c2 = q.z - bf2f(xh.z), d2 = q.w - bf2f(xh.w);
        part += a * a + b * b + c2 * c2 + d2 * d2;
    }
#pragma unroll
    for (int off = 32; off > 0; off >>= 1) part += __shfl_down(part, off, 64);
    if (lane == 0) wsum[wave] = part;
    __syncthreads();
    if (tid == 0) atomicAdd(lossAcc, wsum[0] + wsum[1] + wsum[2] + wsum[3]);
}

__global__ void vq_final_kernel(const float* __restrict__ lossAcc, float* __restrict__ outLoss) {
    *outLoss = 1.25f * (*lossAcc) / 16777216.f;  // q_latent + 0.25*e_latent
}

extern "C" void kernel_launch(void* const* d_in, const int* in_sizes, int n_in,
                              void* d_out, int out_size, void* d_ws, size_t ws_size,
                              hipStream_t stream) {
    const float* x  = (const float*)d_in[0];
    const float* cb = (const float*)d_in[1];
    float* out = (float*)d_out;

    float* cnorm = (float*)d_ws;                                  // 4KB
    float* lossAcc = cnorm + K;                                   // @4KB
    unsigned short* cbf = (unsigned short*)((char*)d_ws + 8192);  // 512KB

    vq_prep<<<K, 64, 0, stream>>>(cb, cnorm, cbf, lossAcc);
    vq_fused<<<NVEC / ROWS, 256, 0, stream>>>(x, cb, cbf, cnorm, lossAcc, out);
    vq_final_kernel<<<1, 1, 0, stream>>>(lossAcc, out + (size_t)NVEC * D);
}